// Round 3
// baseline (443.745 us; speedup 1.0000x reference)
//
#include <hip/hip_runtime.h>
#include <float.h>

#define NB 16
#define NH 16
#define SS 577
#define DD 1024
#define NSEL 257           // NUM_COUNT + 1
#define TOPK 64            // per-head candidate list length
#define PH 16              // picks per head = NUM_COUNT / H

#define HIDDEN_ELEMS (NB * SS * DD)     // 9,453,568 floats
#define HIDDEN_V4 (HIDDEN_ELEMS / 4)
#define SEL_ELEMS (NB * NSEL * DD)      // 4,210,688 floats
#define SEL_V4 (SEL_ELEMS / 4)
#define NCOPY 1792

using f32x4 = __attribute__((ext_vector_type(4))) float;

__device__ __forceinline__ void pair_max_reduce(float& bv, int& bi) {
    // max by (value desc, index asc) across 64 lanes; result in all lanes
    #pragma unroll
    for (int off = 1; off < 64; off <<= 1) {
        float ov = __shfl_xor(bv, off, 64);
        int   oi = __shfl_xor(bi, off, 64);
        if (ov > bv || (ov == bv && oi < bi)) { bv = ov; bi = oi; }
    }
}

// K1: blocks [0,256): per-(b,h) top-64 sorted candidates; the 16th finisher
//     of each batch also does the sequential per-head set-union merge.
//     blocks [256, 256+NCOPY): grid-stride float4 copy hidden -> out[0:HIDDEN].
__global__ __launch_bounds__(256)
void k_sel_copy(const float* __restrict__ hidden,
                const float* __restrict__ attn,
                float* __restrict__ out,
                int* __restrict__ cand,
                int* __restrict__ sel,
                unsigned int* __restrict__ cnt) {
    int blk = blockIdx.x;
    if (blk < NB * NH) {
        if (threadIdx.x >= 64) return;   // single-wave path, no barriers
        int lane = threadIdx.x;
        int b = blk >> 4;
        unsigned long long lowmask = (lane == 0) ? 0ull : ((1ull << lane) - 1ull);

        // ---- per-head top-64 (value desc, index asc) ----
        const float* row = attn + (size_t)blk * ((size_t)SS * SS);  // CLS row
        float v[9];
        #pragma unroll
        for (int s = 0; s < 9; ++s) v[s] = row[1 + lane + 64 * s];  // idx 1..576

        float bv = -FLT_MAX; int bi = 0x7fffffff;
        #pragma unroll
        for (int s = 0; s < 9; ++s)
            if (v[s] > bv) { bv = v[s]; bi = 1 + lane + 64 * s; }

        int mine = 0;
        for (int t = 0; t < TOPK; ++t) {
            float wv = bv; int wi = bi;
            pair_max_reduce(wv, wi);
            if (lane == t) mine = wi;
            int wl = (wi - 1) & 63;
            if (lane == wl) {
                int wslot = (wi - 1) >> 6;
                #pragma unroll
                for (int s = 0; s < 9; ++s) if (s == wslot) v[s] = -FLT_MAX;
                bv = -FLT_MAX; bi = 0x7fffffff;
                #pragma unroll
                for (int s = 0; s < 9; ++s)
                    if (v[s] > bv) { bv = v[s]; bi = 1 + lane + 64 * s; }
            }
        }
        cand[blk * TOPK + lane] = mine;

        // ---- completion count; 16th finisher merges this batch ----
        __threadfence();
        int old = 0;
        if (lane == 0) old = (int)atomicAdd(&cnt[b], 1u);
        old = __shfl(old, 0, 64);
        if (old != NH - 1) return;
        __threadfence();  // acquire: other blocks' cand now visible

        __shared__ unsigned char member[SS];
        for (int i = lane; i < SS; i += 64) member[i] = 0;
        if (lane == 0) member[0] = 1;
        __builtin_amdgcn_wave_barrier();

        for (int h = 0; h < NH; ++h) {
            int c = cand[(b * NH + h) * TOPK + lane];
            int avail = member[c] ? 0 : 1;
            unsigned long long bal = __ballot(avail);
            int rank = __popcll(bal & lowmask);
            if (avail && rank < PH) member[c] = 1;
            int got = __popcll(bal);
            if (got < PH) {
                // exact argmax continuation (astronomically rare; keeps exactness)
                int need = PH - got;
                const float* hrow = attn + (size_t)(b * NH + h) * ((size_t)SS * SS);
                float w[9];
                #pragma unroll
                for (int s = 0; s < 9; ++s) {
                    int idx = 1 + lane + 64 * s;
                    w[s] = member[idx] ? -FLT_MAX : hrow[idx];
                }
                for (int t = 0; t < need; ++t) {
                    float fv = -FLT_MAX; int fi = 0x7fffffff;
                    #pragma unroll
                    for (int s = 0; s < 9; ++s)
                        if (w[s] > fv) { fv = w[s]; fi = 1 + lane + 64 * s; }
                    pair_max_reduce(fv, fi);
                    int wl = (fi - 1) & 63;
                    if (lane == wl) {
                        int wslot = (fi - 1) >> 6;
                        #pragma unroll
                        for (int s = 0; s < 9; ++s) if (s == wslot) w[s] = -FLT_MAX;
                        member[fi] = 1;
                    }
                    __builtin_amdgcn_wave_barrier();
                }
            }
            __builtin_amdgcn_wave_barrier();
        }

        // emit sorted member list (ascending) via chunked ballot prefix
        int pos = 0;
        #pragma unroll
        for (int s = 0; s < 10; ++s) {
            int i = s * 64 + lane;
            int m = (i < SS) ? (member[i] ? 1 : 0) : 0;
            unsigned long long bal = __ballot(m);
            int rank = __popcll(bal & lowmask);
            if (m) sel[b * NSEL + pos + rank] = i;
            pos += __popcll(bal);
        }
    } else {
        const f32x4* src = (const f32x4*)hidden;
        f32x4* dst = (f32x4*)out;
        size_t stride = (size_t)NCOPY * blockDim.x;
        for (size_t i = (size_t)(blk - NB * NH) * blockDim.x + threadIdx.x;
             i < (size_t)HIDDEN_V4; i += stride)
            __builtin_nontemporal_store(src[i], &dst[i]);  // keep hidden cached, not the copy
    }
}

// K2: gather selected rows -> out[HIDDEN:]. Reads are L3-resident (hidden was
// just streamed through cache by K1's loads); writes nontemporal.
__global__ __launch_bounds__(256)
void k_gather(const float* __restrict__ hidden,
              const int* __restrict__ sel,
              float* __restrict__ out) {
    const f32x4* src = (const f32x4*)hidden;
    f32x4* dst = (f32x4*)(out + (size_t)HIDDEN_ELEMS);
    size_t stride = (size_t)gridDim.x * blockDim.x;
    for (size_t i = (size_t)blockIdx.x * blockDim.x + threadIdx.x;
         i < (size_t)SEL_V4; i += stride) {
        size_t rowi = i >> 8;                 // 256 float4 per D=1024 row
        int d4 = (int)(i & 255);
        int b = (int)(rowi / NSEL);
        int j = (int)(rowi - (size_t)b * NSEL);
        int r = sel[b * NSEL + j];
        __builtin_nontemporal_store(src[(((size_t)(b * SS + r)) << 8) + d4], &dst[i]);
    }
}

extern "C" void kernel_launch(void* const* d_in, const int* in_sizes, int n_in,
                              void* d_out, int out_size, void* d_ws, size_t ws_size,
                              hipStream_t stream) {
    const float* hidden = (const float*)d_in[0];  // [16,577,1024] f32
    const float* attn   = (const float*)d_in[1];  // [16,16,577,577] f32
    float* out = (float*)d_out;
    int* cand = (int*)d_ws;                       // [256][64] int
    int* sel  = cand + NB * NH * TOPK;            // [16][257] int
    unsigned int* cnt = (unsigned int*)(sel + NB * NSEL);  // [16] u32

    hipMemsetAsync(cnt, 0, NB * sizeof(unsigned int), stream);
    k_sel_copy<<<NB * NH + NCOPY, 256, 0, stream>>>(hidden, attn, out, cand, sel, cnt);
    k_gather<<<1024, 256, 0, stream>>>(hidden, sel, out);
}